// Round 9
// baseline (1342.330 us; speedup 1.0000x reference)
//
#include <hip/hip_runtime.h>

#define NBATCH 256
#define SLEN   2048
#define NTAG   64
#define BOS_T  1
#define EOS_T  2

#define BT_BYTES 131072
// pv: val[3][4][64] f32 (3072 B) + idx[3][4][64] u32 (3072 B)
#define PV_BYTES 6144
#define LDS_BYTES (BT_BYTES + PV_BYTES)

__device__ __forceinline__ float lane_bcast(float v, int lane) {
    return __uint_as_float(__builtin_amdgcn_readlane(__float_as_uint(v), lane));
}

#define K16(X) X(0) X(1) X(2) X(3) X(4) X(5) X(6) X(7) \
               X(8) X(9) X(10) X(11) X(12) X(13) X(14) X(15)

#define DECL_TC(k) float tcv##k = trans[(pbase + k) * NTAG + c];
#define KEEP_TC(k) asm volatile("" : "+v"(tcv##k));
// candidate k for this wave's prev range
#define CAND(k)    float cd##k = lane_bcast(a, pbase + k) + tcv##k;
// local argmax chain, ascending k, strict > keeps first occurrence.
// value update via fmaxf (v_max, no mask); only the index select uses a mask.
#define ICH(k)     { bool g_ = (cd##k > bv); bi = g_ ? (pbase + k) : bi; \
                     bv = fmaxf(bv, cd##k); }

__global__ __launch_bounds__(256)
__attribute__((amdgpu_waves_per_eu(1, 1)))
void crf_viterbi(const float* __restrict__ emissions,  // [B,S,C]
                 const float* __restrict__ mask,       // [B,S]
                 const float* __restrict__ trans,      // [C,C]
                 int* __restrict__ out)                // [B,S] int32 tags
{
    extern __shared__ unsigned char lds[];
    unsigned char* bt = lds;                        // [S-1][64] backpointers
    float*    pval = (float*)(lds + BT_BYTES);      // [3][4][64]
    unsigned* pidx = (unsigned*)(lds + BT_BYTES + 3072);  // [3][4][64]

    const int b   = blockIdx.x;
    const int tid = threadIdx.x;
    const int w   = tid >> 6;                       // wave id 0..3
    const int c   = tid & 63;                       // current tag
    const int pbase = w << 4;                       // prev range base
    const int wslot = (w << 6) + c;

    K16(DECL_TC)                                    // 16 T entries per wave

    // length = sum(mask[b,:])
    const float* mrow = mask + (size_t)b * SLEN;
    float msum = 0.f;
    #pragma unroll
    for (int k = 0; k < SLEN / 64; ++k) msum += mrow[c + k * 64];
    #pragma unroll
    for (int off = 32; off >= 1; off >>= 1) msum += __shfl_xor(msum, off, 64);
    const int len = (int)msum;                      // in [1024, 2048]

    const float* E = emissions + (size_t)b * SLEN * NTAG;

    // alpha replica in lane registers; identical in all 4 waves
    float a = E[c] + trans[BOS_T * NTAG + c];

    // depth-4 emissions prefetch (never drained: raw barrier has no vmcnt wait)
    float e0 = E[NTAG + c];
    float e1 = E[((2 < len) ? 2 : (len - 1)) * NTAG + c];
    float e2 = E[((3 < len) ? 3 : (len - 1)) * NTAG + c];
    float e3 = E[((4 < len) ? 4 : (len - 1)) * NTAG + c];

    int s_cur = 1, s_lag = 0;                       // t%3, (t-1)%3
    for (int t = 1; t < len; ++t) {
        K16(KEEP_TC)                                // pin tc in VGPRs

        float emit = e0; e0 = e1; e1 = e2; e2 = e3;
        int tn = (t + 4 < len) ? (t + 4) : (len - 1);
        e3 = E[tn * NTAG + c];

        K16(CAND)

        // ---- critical value path: pure v_max tree (no masks, exact) ----
        float m0 = fmaxf(cd0,  cd1),  m1 = fmaxf(cd2,  cd3);
        float m2 = fmaxf(cd4,  cd5),  m3 = fmaxf(cd6,  cd7);
        float m4 = fmaxf(cd8,  cd9),  m5 = fmaxf(cd10, cd11);
        float m6 = fmaxf(cd12, cd13), m7 = fmaxf(cd14, cd15);
        float n0 = fmaxf(m0, m1), n1 = fmaxf(m2, m3);
        float n2 = fmaxf(m4, m5), n3 = fmaxf(m6, m7);
        float vw = fmaxf(fmaxf(n0, n1), fmaxf(n2, n3));
        pval[(s_cur << 8) + wslot] = vw;

        // ---- index path (off the serial cycle): strict-> ascending chain ----
        float bv = cd0; int bi = pbase;
        ICH(1)  ICH(2)  ICH(3)  ICH(4)  ICH(5)  ICH(6)  ICH(7)
        ICH(8)  ICH(9)  ICH(10) ICH(11) ICH(12) ICH(13) ICH(14) ICH(15)
        pidx[(s_cur << 8) + wslot] = (unsigned)bi;

        // drain own LDS writes, raw barrier (no vmcnt drain)
        asm volatile("s_waitcnt lgkmcnt(0)\n\ts_barrier" ::: "memory");

        // ---- critical: merge 4 value partials, update alpha ----
        float v0 = pval[(s_cur << 8) + c];
        float v1 = pval[(s_cur << 8) + 64 + c];
        float v2 = pval[(s_cur << 8) + 128 + c];
        float v3 = pval[(s_cur << 8) + 192 + c];
        a = fmaxf(fmaxf(v0, v1), fmaxf(v2, v3)) + emit;

        // ---- lagged backpointer merge for step t-1 (slot s_lag) ----
        float    l0 = pval[(s_lag << 8) + c];
        float    l1 = pval[(s_lag << 8) + 64 + c];
        float    l2 = pval[(s_lag << 8) + 128 + c];
        float    l3 = pval[(s_lag << 8) + 192 + c];
        unsigned j0 = pidx[(s_lag << 8) + c];
        unsigned j1 = pidx[(s_lag << 8) + 64 + c];
        unsigned j2 = pidx[(s_lag << 8) + 128 + c];
        unsigned j3 = pidx[(s_lag << 8) + 192 + c];
        float gb = l0; unsigned gi = j0;
        { bool g = (l1 > gb); gi = g ? j1 : gi; gb = fmaxf(gb, l1); }
        { bool g = (l2 > gb); gi = g ? j2 : gi; gb = fmaxf(gb, l2); }
        { bool g = (l3 > gb); gi = g ? j3 : gi; gb = fmaxf(gb, l3); }
        if (w == 0 && t >= 2) bt[(t - 2) * NTAG + c] = (unsigned char)gi;

        s_lag = s_cur;
        s_cur = (s_cur == 2) ? 0 : (s_cur + 1);
    }

    // flush bt row len-2 from the last step's partials (slot s_lag)
    {
        float    l0 = pval[(s_lag << 8) + c];
        float    l1 = pval[(s_lag << 8) + 64 + c];
        float    l2 = pval[(s_lag << 8) + 128 + c];
        float    l3 = pval[(s_lag << 8) + 192 + c];
        unsigned j0 = pidx[(s_lag << 8) + c];
        unsigned j1 = pidx[(s_lag << 8) + 64 + c];
        unsigned j2 = pidx[(s_lag << 8) + 128 + c];
        unsigned j3 = pidx[(s_lag << 8) + 192 + c];
        float gb = l0; unsigned gi = j0;
        { bool g = (l1 > gb); gi = g ? j1 : gi; gb = fmaxf(gb, l1); }
        { bool g = (l2 > gb); gi = g ? j2 : gi; gb = fmaxf(gb, l2); }
        { bool g = (l3 > gb); gi = g ? j3 : gi; gb = fmaxf(gb, l3); }
        if (w == 0) bt[(len - 2) * NTAG + c] = (unsigned char)gi;
    }

    // final scores: alpha + T[:,EOS]
    float fin = a + trans[c * NTAG + EOS_T];

    // wave argmax: value desc, index asc (first occurrence); same in all waves
    float v = fin; int idx = c;
    #pragma unroll
    for (int off = 1; off < 64; off <<= 1) {
        float ov = __shfl_xor(v, off, 64);
        int   oi = __shfl_xor(idx, off, 64);
        if (ov > v || (ov == v && oi < idx)) { v = ov; idx = oi; }
    }
    int cur = idx;                                  // best_last (uniform)

    int* orow = out + (size_t)b * SLEN;
    for (int t = len + tid; t < SLEN; t += 256) orow[t] = 0;   // PAD tail

    if (w != 0) return;
    if (c == 0) orow[len - 1] = cur;

    // drain wave0's bt writes, then chase backpointers (uniform broadcast reads)
    asm volatile("s_waitcnt lgkmcnt(0)" ::: "memory");
    for (int t = len - 2; t >= 0; --t) {
        cur = bt[t * NTAG + cur];
        if (c == 0) orow[t] = cur;
    }
}

extern "C" void kernel_launch(void* const* d_in, const int* in_sizes, int n_in,
                              void* d_out, int out_size, void* d_ws, size_t ws_size,
                              hipStream_t stream) {
    const float* emissions = (const float*)d_in[0];
    const float* mask      = (const float*)d_in[1];
    const float* trans     = (const float*)d_in[2];
    int* out = (int*)d_out;

    (void)hipFuncSetAttribute((const void*)crf_viterbi,
                              hipFuncAttributeMaxDynamicSharedMemorySize,
                              LDS_BYTES);

    crf_viterbi<<<NBATCH, 256, LDS_BYTES, stream>>>(emissions, mask, trans, out);
}

// Round 10
// 1021.053 us; speedup vs baseline: 1.3147x; 1.3147x over previous
//
#include <hip/hip_runtime.h>

#define NBATCH 256
#define SLEN   2048
#define NTAG   64
#define BOS_T  1
#define EOS_T  2

#define BT_BYTES 131072
// pv: 2 bufs x 8 waves x 64 x 8B (uint2 {val,idx}) = 8192
#define PV_BYTES 8192
#define LDS_BYTES (BT_BYTES + PV_BYTES)

__device__ __forceinline__ float lane_bcast(float v, int lane) {
    return __uint_as_float(__builtin_amdgcn_readlane(__float_as_uint(v), lane));
}

#define K8(X) X(0) X(1) X(2) X(3) X(4) X(5) X(6) X(7)

#define DECL_TC(k) float tcv##k = trans[(pbase + k) * NTAG + c];
#define KEEP_TC(k) asm volatile("" : "+v"(tcv##k));
#define CAND(k)    float cd##k = lane_bcast(a, pbase + k) + tcv##k;

// tournament leaf over candidates ka<kb; >= keeps lower index on ties
#define LEAF(i, ka, kb) \
  float va##i; int ia##i; { bool g_ = (cd##ka >= cd##kb); \
    va##i = g_ ? cd##ka : cd##kb; ia##i = g_ ? (pbase + ka) : (pbase + kb); }

// merge node: A holds lower indices; >= keeps A on ties
#define MRG(vo, io, vA, iA, vB, iB) \
  float vo; int io; { bool g_ = ((vA) >= (vB)); \
    vo = g_ ? (vA) : (vB); io = g_ ? (iA) : (iB); }

// 8 waves (2 per SIMD): prev-range split 8/wave. With 1 wave/SIMD (r7-r9),
// dependent VALU chains run at ~4cyc/instr (nothing to interleave); two
// waves/SIMD overlap chains -> ~2cyc effective. 131KB LDS -> 1 wg/CU.
__global__ __launch_bounds__(512)
__attribute__((amdgpu_waves_per_eu(2, 2)))
void crf_viterbi(const float* __restrict__ emissions,  // [B,S,C]
                 const float* __restrict__ mask,       // [B,S]
                 const float* __restrict__ trans,      // [C,C]
                 int* __restrict__ out)                // [B,S] int32 tags
{
    extern __shared__ unsigned char lds[];
    unsigned char* bt = lds;                    // [S-1][64] backpointers
    uint2* pv = (uint2*)(lds + BT_BYTES);       // [2][8][64] {val,idx}

    const int b   = blockIdx.x;
    const int tid = threadIdx.x;
    const int w   = tid >> 6;                   // wave id 0..7
    const int c   = tid & 63;                   // current tag
    const int pbase = w << 3;                   // this wave's 8-prev base

    K8(DECL_TC)                                 // 8 T entries per wave

    // length = sum(mask[b,:])
    const float* mrow = mask + (size_t)b * SLEN;
    float msum = 0.f;
    #pragma unroll
    for (int k = 0; k < SLEN / 64; ++k) msum += mrow[c + k * 64];
    #pragma unroll
    for (int off = 32; off >= 1; off >>= 1) msum += __shfl_xor(msum, off, 64);
    const int len = (int)msum;                  // in [1024, 2048]

    const float* E = emissions + (size_t)b * SLEN * NTAG;

    // alpha replica in lane registers; identical in all 8 waves
    float a = E[c] + trans[BOS_T * NTAG + c];

    // depth-4 emissions prefetch (raw barrier below never drains vmcnt)
    float e0 = E[NTAG + c];
    float e1 = E[((2 < len) ? 2 : (len - 1)) * NTAG + c];
    float e2 = E[((3 < len) ? 3 : (len - 1)) * NTAG + c];
    float e3 = E[((4 < len) ? 4 : (len - 1)) * NTAG + c];

    for (int t = 1; t < len; ++t) {
        K8(KEEP_TC)                             // pin tc in VGPRs

        float emit = e0; e0 = e1; e1 = e2; e2 = e3;
        int tn = (t + 4 < len) ? (t + 4) : (len - 1);
        e3 = E[tn * NTAG + c];

        K8(CAND)

        // 8-candidate tournament (exact first-occurrence argmax)
        LEAF(0, 0, 1)  LEAF(1, 2, 3)  LEAF(2, 4, 5)  LEAF(3, 6, 7)
        MRG(vb0, ib0, va0, ia0, va1, ia1)
        MRG(vb1, ib1, va2, ia2, va3, ia3)
        MRG(vw, iw, vb0, ib0, vb1, ib1)

        // publish partial (double-buffered; single barrier per step is safe)
        uint2* pvbuf = pv + ((t & 1) << 9);
        uint2 mine; mine.x = __float_as_uint(vw); mine.y = (unsigned)iw;
        pvbuf[(w << 6) + c] = mine;

        asm volatile("s_waitcnt lgkmcnt(0)\n\ts_barrier" ::: "memory");

        // merge 8 partials, ascending wave order (left bias = lower prevs)
        uint2 q0 = pvbuf[c];
        uint2 q1 = pvbuf[64 + c];
        uint2 q2 = pvbuf[128 + c];
        uint2 q3 = pvbuf[192 + c];
        uint2 q4 = pvbuf[256 + c];
        uint2 q5 = pvbuf[320 + c];
        uint2 q6 = pvbuf[384 + c];
        uint2 q7 = pvbuf[448 + c];
        float f0 = __uint_as_float(q0.x); int j0 = (int)q0.y;
        float f1 = __uint_as_float(q1.x); int j1 = (int)q1.y;
        float f2 = __uint_as_float(q2.x); int j2 = (int)q2.y;
        float f3 = __uint_as_float(q3.x); int j3 = (int)q3.y;
        float f4 = __uint_as_float(q4.x); int j4 = (int)q4.y;
        float f5 = __uint_as_float(q5.x); int j5 = (int)q5.y;
        float f6 = __uint_as_float(q6.x); int j6 = (int)q6.y;
        float f7 = __uint_as_float(q7.x); int j7 = (int)q7.y;
        MRG(ma0, na0, f0, j0, f1, j1)
        MRG(ma1, na1, f2, j2, f3, j3)
        MRG(ma2, na2, f4, j4, f5, j5)
        MRG(ma3, na3, f6, j6, f7, j7)
        MRG(mb0, nb0, ma0, na0, ma1, na1)
        MRG(mb1, nb1, ma2, na2, ma3, na3)
        MRG(mc0, nc0, mb0, nb0, mb1, nb1)

        a = mc0 + emit;                         // identical in all waves
        if (w == 0) bt[(t - 1) * NTAG + c] = (unsigned char)nc0;
    }

    // final scores: alpha + T[:,EOS]
    float fin = a + trans[c * NTAG + EOS_T];

    // wave argmax: value desc, index asc (first occurrence); same in all waves
    float v = fin; int idx = c;
    #pragma unroll
    for (int off = 1; off < 64; off <<= 1) {
        float ov = __shfl_xor(v, off, 64);
        int   oi = __shfl_xor(idx, off, 64);
        if (ov > v || (ov == v && oi < idx)) { v = ov; idx = oi; }
    }
    int cur = idx;                              // best_last (uniform)

    int* orow = out + (size_t)b * SLEN;
    for (int t = len + tid; t < SLEN; t += 512) orow[t] = 0;   // PAD tail

    if (w != 0) return;                         // no barriers remain
    if (c == 0) orow[len - 1] = cur;

    // drain wave0's bt writes, then chase backpointers (uniform broadcast)
    asm volatile("s_waitcnt lgkmcnt(0)" ::: "memory");
    for (int t = len - 2; t >= 0; --t) {
        cur = bt[t * NTAG + cur];
        if (c == 0) orow[t] = cur;
    }
}

extern "C" void kernel_launch(void* const* d_in, const int* in_sizes, int n_in,
                              void* d_out, int out_size, void* d_ws, size_t ws_size,
                              hipStream_t stream) {
    const float* emissions = (const float*)d_in[0];
    const float* mask      = (const float*)d_in[1];
    const float* trans     = (const float*)d_in[2];
    int* out = (int*)d_out;

    (void)hipFuncSetAttribute((const void*)crf_viterbi,
                              hipFuncAttributeMaxDynamicSharedMemorySize,
                              LDS_BYTES);

    crf_viterbi<<<NBATCH, 512, LDS_BYTES, stream>>>(emissions, mask, trans, out);
}

// Round 11
// 1015.806 us; speedup vs baseline: 1.3214x; 1.0052x over previous
//
#include <hip/hip_runtime.h>

#define NBATCH 256
#define SLEN   2048
#define NTAG   64
#define BOS_T  1
#define EOS_T  2

#define BT_BYTES 131072
#define AL_BYTES 512               // alpha: 2 bufs x 64 f32
#define LDS_BYTES (BT_BYTES + AL_BYTES)

typedef float f32x4 __attribute__((ext_vector_type(4)));

#define K8(X) X(0) X(1) X(2) X(3) X(4) X(5) X(6) X(7)
#define DECL_TC(k) float tcv##k = trans[(pbase + k) * NTAG + c];
#define KEEP_TC(k) asm volatile("" : "+v"(tcv##k));

// tournament leaf: local prevs ka<kb; >= keeps lower index on ties
#define LEAF(i, ka, kb) \
  float va##i; int ia##i; { bool g_ = (cd##ka >= cd##kb); \
    va##i = g_ ? cd##ka : cd##kb; ia##i = g_ ? ka : kb; }
#define MRG(vo, io, vA, iA, vB, iB) \
  float vo; int io; { bool g_ = ((vA) >= (vB)); \
    vo = g_ ? (vA) : (vB); io = g_ ? (iA) : (iB); }

// butterfly combine across p_hi groups (lane-id bit); lower p_hi wins ties
#define CMB(bit) { \
    float ov = __shfl_xor(gv, bit, 64); \
    int   oi = __shfl_xor(gi, bit, 64); \
    bool lo = ((lane & bit) == 0); \
    float lv = lo ? gv : ov, hv = lo ? ov : gv; \
    int   li = lo ? gi : oi, hj = lo ? oi : gi; \
    bool g_ = (lv >= hv); \
    gv = g_ ? lv : hv; gi = g_ ? li : hj; }

// c-split: 8 waves x 8 output tags; lane = (p_hi, c_local), 8 prevs/lane.
// Cross-prev combine is an IN-WAVE shfl butterfly (no LDS); only alpha
// crosses waves: 1 ds_write_b32 + 2 ds_read_b128 per wave per step
// (r10's prev-split needed 64 ds_read_b64/CU/step -> LDS-pipe-bound).
__global__ __launch_bounds__(512)
__attribute__((amdgpu_waves_per_eu(2, 2)))
void crf_viterbi(const float* __restrict__ emissions,  // [B,S,C]
                 const float* __restrict__ mask,       // [B,S]
                 const float* __restrict__ trans,      // [C,C]
                 int* __restrict__ out)                // [B,S] int32 tags
{
    extern __shared__ unsigned char lds[];
    unsigned char* bt = lds;                  // [S-1][64] backpointers
    float* abuf = (float*)(lds + BT_BYTES);   // [2][64] alpha ping-pong

    const int b     = blockIdx.x;
    const int tid   = threadIdx.x;
    const int w     = tid >> 6;               // wave id 0..7
    const int lane  = tid & 63;
    const int p_hi  = lane >> 3;              // prev group 0..7
    const int cl    = lane & 7;
    const int c     = (w << 3) + cl;          // this lane's output tag
    const int pbase = p_hi << 3;              // this lane's prev base

    K8(DECL_TC)                               // 8 T entries: T[pbase+k][c]

    // length = sum(mask[b,:])
    const float* mrow = mask + (size_t)b * SLEN;
    float msum = 0.f;
    #pragma unroll
    for (int k = 0; k < SLEN / 64; ++k) msum += mrow[lane + k * 64];
    #pragma unroll
    for (int off = 32; off >= 1; off >>= 1) msum += __shfl_xor(msum, off, 64);
    const int len = (int)msum;                // in [1024, 2048]

    const float* E = emissions + (size_t)b * SLEN * NTAG;

    // alpha[0] into buf 0 (lanes p_hi==0 of each wave cover all 64 tags)
    if (p_hi == 0) abuf[c] = E[c] + trans[BOS_T * NTAG + c];
    asm volatile("s_waitcnt lgkmcnt(0)\n\ts_barrier" ::: "memory");

    // depth-4 emissions prefetch for own c (x8 dup across p_hi; coalesced)
    float e0 = E[NTAG + c];
    float e1 = E[((2 < len) ? 2 : (len - 1)) * NTAG + c];
    float e2 = E[((3 < len) ? 3 : (len - 1)) * NTAG + c];
    float e3 = E[((4 < len) ? 4 : (len - 1)) * NTAG + c];

    for (int t = 1; t < len; ++t) {
        K8(KEEP_TC)                           // pin tc in VGPRs

        float emit = e0; e0 = e1; e1 = e2; e2 = e3;
        int tn = (t + 4 < len) ? (t + 4) : (len - 1);
        e3 = E[tn * NTAG + c];

        // read this lane's 8 prev alphas (2-way bank alias = free)
        const f32x4* ab = (const f32x4*)(abuf + ((t ^ 1) & 1) * NTAG);
        f32x4 al0 = ab[(p_hi << 1)];
        f32x4 al1 = ab[(p_hi << 1) + 1];
        float cd0 = al0[0] + tcv0, cd1 = al0[1] + tcv1;
        float cd2 = al0[2] + tcv2, cd3 = al0[3] + tcv3;
        float cd4 = al1[0] + tcv4, cd5 = al1[1] + tcv5;
        float cd6 = al1[2] + tcv6, cd7 = al1[3] + tcv7;

        // local 8-candidate tournament (exact first-occurrence)
        LEAF(0, 0, 1) LEAF(1, 2, 3) LEAF(2, 4, 5) LEAF(3, 6, 7)
        MRG(vb0, ib0, va0, ia0, va1, ia1)
        MRG(vb1, ib1, va2, ia2, va3, ia3)
        MRG(vt, it, vb0, ib0, vb1, ib1)

        float gv = vt; int gi = pbase + it;
        CMB(8) CMB(16) CMB(32)                // combine 8 prev-groups in-wave

        float anew = gv + emit;
        if (p_hi == 0) {
            abuf[(t & 1) * NTAG + c] = anew;              // publish alpha[t]
            bt[(t - 1) * NTAG + c] = (unsigned char)gi;   // backpointer
        }
        asm volatile("s_waitcnt lgkmcnt(0)\n\ts_barrier" ::: "memory");
    }

    // final scores from last alpha buffer (visible after loop's last barrier)
    const float* afin = abuf + (((len - 1) & 1) * NTAG);

    int* orow = out + (size_t)b * SLEN;
    for (int i = len + tid; i < SLEN; i += 512) orow[i] = 0;   // PAD tail

    if (w != 0) return;                        // no barriers remain

    // wave 0: final argmax (value desc, index asc) over fin = alpha + T[:,EOS]
    float fin = afin[lane] + trans[lane * NTAG + EOS_T];
    float v = fin; int idx = lane;
    #pragma unroll
    for (int off = 1; off < 64; off <<= 1) {
        float ov = __shfl_xor(v, off, 64);
        int   oi = __shfl_xor(idx, off, 64);
        if (ov > v || (ov == v && oi < idx)) { v = ov; idx = oi; }
    }
    int cur = idx;                             // best_last (uniform)

    if (lane == 0) orow[len - 1] = cur;

    // backtrace through LDS backpointers (uniform broadcast reads)
    asm volatile("s_waitcnt lgkmcnt(0)" ::: "memory");
    for (int t = len - 2; t >= 0; --t) {
        cur = bt[t * NTAG + cur];
        if (lane == 0) orow[t] = cur;
    }
}

extern "C" void kernel_launch(void* const* d_in, const int* in_sizes, int n_in,
                              void* d_out, int out_size, void* d_ws, size_t ws_size,
                              hipStream_t stream) {
    const float* emissions = (const float*)d_in[0];
    const float* mask      = (const float*)d_in[1];
    const float* trans     = (const float*)d_in[2];
    int* out = (int*)d_out;

    (void)hipFuncSetAttribute((const void*)crf_viterbi,
                              hipFuncAttributeMaxDynamicSharedMemorySize,
                              LDS_BYTES);

    crf_viterbi<<<NBATCH, 512, LDS_BYTES, stream>>>(emissions, mask, trans, out);
}